// Round 14
// baseline (674.953 us; speedup 1.0000x reference)
//
#include <hip/hip_runtime.h>
#include <cstdint>
#include <math.h>

typedef _Float16 f16;
typedef __attribute__((ext_vector_type(4))) _Float16 f16x4;
typedef __attribute__((ext_vector_type(8))) _Float16 f16x8;
typedef __attribute__((ext_vector_type(4))) float f32x4;

// ---------------------------------------------------------------- helpers
__device__ inline void gload_lds16(const void* g, void* l) {
  auto gp = reinterpret_cast<const __attribute__((address_space(1))) uint32_t*>(
      reinterpret_cast<uintptr_t>(g));
  auto lp = reinterpret_cast<__attribute__((address_space(3))) uint32_t*>(
      reinterpret_cast<uintptr_t>(l));
  __builtin_amdgcn_global_load_lds(gp, lp, 16 /*bytes*/, 0, 0);
}

// ---------------------------------------------------------------- fused fp32->f16 converts + zero-fill
// Ranges: hidden (4194304 f4) | cross (6557696) | wqkv (6291456) | wo (nwo: 0 or
// 4194304) | zero K/Vt (1703936 x16B)
__global__ __launch_bounds__(256) void cvtzero_kernel(const float* __restrict__ s0, f16* __restrict__ d0,
                                                      const float* __restrict__ s1, f16* __restrict__ d1,
                                                      const float* __restrict__ s2, f16* __restrict__ d2,
                                                      const float* __restrict__ s3, f16* __restrict__ d3,
                                                      int nwo,
                                                      float4* __restrict__ z) {
  int idx = blockIdx.x * blockDim.x + threadIdx.x;
  int stride = gridDim.x * blockDim.x;
  const int nz0 = 17043456 + nwo;
  const int total = nz0 + 1703936;
  for (int i = idx; i < total; i += stride) {
    const float* src; f16* dst; int k;
    if (i < 4194304) { src = s0; dst = d0; k = i; }
    else if (i < 10752000) { src = s1; dst = d1; k = i - 4194304; }
    else if (i < 17043456) { src = s2; dst = d2; k = i - 10752000; }
    else if (i < nz0) { src = s3; dst = d3; k = i - 17043456; }
    else { float4 zr = {0.f, 0.f, 0.f, 0.f}; z[i - nz0] = zr; continue; }
    float4 v = reinterpret_cast<const float4*>(src)[k];
    f16x4 h;
    h.x = (f16)v.x; h.y = (f16)v.y; h.z = (f16)v.z; h.w = (f16)v.w;
    reinterpret_cast<f16x4*>(dst)[k] = h;
  }
}

// ---------------------------------------------------------------- plain fp32 -> f16 convert (wo fallback)
__global__ __launch_bounds__(256) void cvt_kernel(const float* __restrict__ src,
                                                  f16* __restrict__ dst, int n4) {
  int idx = blockIdx.x * blockDim.x + threadIdx.x;
  int stride = gridDim.x * blockDim.x;
  for (int i = idx; i < n4; i += stride) {
    float4 v = reinterpret_cast<const float4*>(src)[i];
    f16x4 h;
    h.x = (f16)v.x; h.y = (f16)v.y; h.z = (f16)v.z; h.w = (f16)v.w;
    reinterpret_cast<f16x4*>(dst)[i] = h;
  }
}

// ---------------------------------------------------------------- 256x256 GEMM, m201-style 4-phase
// (r12 state -- verified) 512 thr / 8 waves (2M x 4N), per-wave 128x64, BK=64,
// LDS 128 KB dbuf, ONE barrier/phase with hoisted ds_reads + staging, counted
// vmcnt(2) at tile entry, setprio around MFMA clusters.
// EPI==0: fp32 C.  EPI==1: per-128-col RMS -> f16 Ch (Q path, scale*log2e).
// EPI==2: KV path (K-half: RMS -> Kf; V-half: transpose -> Vtf).
template <bool MB, int EPI>
__global__ __launch_bounds__(512, 2) void gemm256(const f16* __restrict__ A,
                                                  const f16* __restrict__ Bw,
                                                  float* __restrict__ C,
                                                  f16* __restrict__ Ch,
                                                  const float* __restrict__ wvec,
                                                  f16* __restrict__ Vtf,
                                                  int M, int N, int K) {
  __shared__ f16 As[2][256][64];
  __shared__ f16 Bs[2][256][64];
  const int tid = threadIdx.x;
  const int l = tid & 63, w = tid >> 6;  // 8 waves
  const int lq = l & 15, lk = l >> 4;
  const int wm = w >> 2, wn = w & 3;     // 2M x 4N wave grid
  const int nwg = gridDim.x * gridDim.y;
  const int p = blockIdx.y * gridDim.x + blockIdx.x;
  const int L = (p & 7) * (nwg >> 3) + (p >> 3);
  const int bx = L % gridDim.x, by = L / gridDim.x;
  const int brow = by * 256, bcol = bx * 256;
  const int KT = K >> 6;

  const int srow8 = w * 8 + (l >> 3);            // + i*64
  const int scol  = ((l & 7) ^ (l >> 3)) * 8;    // pre-swizzled source col (f16)
  const int swz   = (lq & 7) << 4;               // read-side XOR

  f32x4 acc[8][4];
  f32x4 zf = {0.f, 0.f, 0.f, 0.f};
#pragma unroll
  for (int m = 0; m < 8; ++m)
#pragma unroll
    for (int n = 0; n < 4; ++n) acc[m][n] = zf;

  auto stageA = [&](int kt, int buf, int i) {
    int ra = brow + i * 64 + srow8;
    if (MB) ra = (ra < M) ? ra : (M - 1);
    gload_lds16(A + (size_t)ra * K + kt * 64 + scol,
                (char*)(&As[buf][0][0]) + i * 8192 + w * 1024);
  };
  auto stageB = [&](int kt, int buf, int i) {
    int rb = bcol + i * 64 + srow8;
    gload_lds16(Bw + (size_t)rb * K + kt * 64 + scol,
                (char*)(&Bs[buf][0][0]) + i * 8192 + w * 1024);
  };
  auto ldA = [&](int buf, int m, int kk) -> f16x8 {
    int r = wm * 128 + m * 16 + lq;
    return *reinterpret_cast<const f16x8*>(
        (char*)(&As[buf][0][0]) + r * 128 + ((kk * 64 + lk * 16) ^ swz));
  };
  auto ldB = [&](int buf, int n, int kk) -> f16x8 {
    int r = wn * 64 + n * 16 + lq;
    return *reinterpret_cast<const f16x8*>(
        (char*)(&Bs[buf][0][0]) + r * 128 + ((kk * 64 + lk * 16) ^ swz));
  };

  // prologue: stage tile 0 (8 issues)
#pragma unroll
  for (int i = 0; i < 4; ++i) stageA(0, 0, i);
#pragma unroll
  for (int i = 0; i < 4; ++i) stageB(0, 0, i);

  f16x8 avA[4][2], avB[4][2], bvA[2][2], bvB[2][2];
  for (int t = 0; t < KT; ++t) {
    const int buf = t & 1, nbuf = buf ^ 1;
    const bool pf = (t + 1 < KT);

    // ---- tile entry: 2 stages ahead, then wait for tile-t's 8
    if (pf) {
      stageA(t + 1, nbuf, 0); stageA(t + 1, nbuf, 1);
      asm volatile("s_waitcnt vmcnt(2)" ::: "memory");
    } else {
      asm volatile("s_waitcnt vmcnt(0)" ::: "memory");
    }
    __builtin_amdgcn_s_barrier();

    // ---- phase 0: (m0-3 x n0-1)
#pragma unroll
    for (int mm = 0; mm < 4; ++mm)
#pragma unroll
      for (int kk = 0; kk < 2; ++kk) avA[mm][kk] = ldA(buf, mm, kk);
#pragma unroll
    for (int nn = 0; nn < 2; ++nn)
#pragma unroll
      for (int kk = 0; kk < 2; ++kk) bvA[nn][kk] = ldB(buf, nn, kk);
    __builtin_amdgcn_s_setprio(1);
#pragma unroll
    for (int mm = 0; mm < 4; ++mm)
#pragma unroll
      for (int nn = 0; nn < 2; ++nn)
#pragma unroll
        for (int kk = 0; kk < 2; ++kk)
          acc[mm][nn] = __builtin_amdgcn_mfma_f32_16x16x32_f16(avA[mm][kk], bvA[nn][kk], acc[mm][nn], 0, 0, 0);
    __builtin_amdgcn_s_setprio(0);
#pragma unroll
    for (int mm = 0; mm < 4; ++mm)
#pragma unroll
      for (int kk = 0; kk < 2; ++kk) avB[mm][kk] = ldA(buf, 4 + mm, kk);
    if (pf) { stageA(t + 1, nbuf, 2); stageA(t + 1, nbuf, 3); }
    asm volatile("" ::: "memory");
    __builtin_amdgcn_s_barrier();

    // ---- phase 1: (m4-7 x n0-1)
    __builtin_amdgcn_s_setprio(1);
#pragma unroll
    for (int mm = 0; mm < 4; ++mm)
#pragma unroll
      for (int nn = 0; nn < 2; ++nn)
#pragma unroll
        for (int kk = 0; kk < 2; ++kk)
          acc[4 + mm][nn] = __builtin_amdgcn_mfma_f32_16x16x32_f16(avB[mm][kk], bvA[nn][kk], acc[4 + mm][nn], 0, 0, 0);
    __builtin_amdgcn_s_setprio(0);
#pragma unroll
    for (int nn = 0; nn < 2; ++nn)
#pragma unroll
      for (int kk = 0; kk < 2; ++kk) bvB[nn][kk] = ldB(buf, 2 + nn, kk);
    if (pf) { stageB(t + 1, nbuf, 0); stageB(t + 1, nbuf, 1); }
    asm volatile("" ::: "memory");
    __builtin_amdgcn_s_barrier();

    // ---- phase 2: (m4-7 x n2-3)
    __builtin_amdgcn_s_setprio(1);
#pragma unroll
    for (int mm = 0; mm < 4; ++mm)
#pragma unroll
      for (int nn = 0; nn < 2; ++nn)
#pragma unroll
        for (int kk = 0; kk < 2; ++kk)
          acc[4 + mm][2 + nn] = __builtin_amdgcn_mfma_f32_16x16x32_f16(avB[mm][kk], bvB[nn][kk], acc[4 + mm][2 + nn], 0, 0, 0);
    __builtin_amdgcn_s_setprio(0);
#pragma unroll
    for (int mm = 0; mm < 4; ++mm)
#pragma unroll
      for (int kk = 0; kk < 2; ++kk) avA[mm][kk] = ldA(buf, mm, kk);
    if (pf) { stageB(t + 1, nbuf, 2); stageB(t + 1, nbuf, 3); }
    asm volatile("" ::: "memory");
    __builtin_amdgcn_s_barrier();

    // ---- phase 3: (m0-3 x n2-3)
    __builtin_amdgcn_s_setprio(1);
#pragma unroll
    for (int mm = 0; mm < 4; ++mm)
#pragma unroll
      for (int nn = 0; nn < 2; ++nn)
#pragma unroll
        for (int kk = 0; kk < 2; ++kk)
          acc[mm][2 + nn] = __builtin_amdgcn_mfma_f32_16x16x32_f16(avA[mm][kk], bvB[nn][kk], acc[mm][2 + nn], 0, 0, 0);
    __builtin_amdgcn_s_setprio(0);
  }

  if (EPI == 0) {
#pragma unroll
    for (int m = 0; m < 8; ++m) {
#pragma unroll
      for (int j = 0; j < 4; ++j) {
        int row = brow + wm * 128 + m * 16 + lk * 4 + j;
        if (MB && row >= M) continue;
        float* dst = C + (size_t)row * N + bcol + wn * 64 + lq;
#pragma unroll
        for (int n = 0; n < 4; ++n) dst[n * 16] = acc[m][n][j];
      }
    }
  } else if (EPI == 1) {
    __shared__ float ssq[256][4];
#pragma unroll
    for (int m = 0; m < 8; ++m)
#pragma unroll
      for (int j = 0; j < 4; ++j) {
        int lr = wm * 128 + m * 16 + lk * 4 + j;
        float pp = 0.f;
#pragma unroll
        for (int n = 0; n < 4; ++n) pp += acc[m][n][j] * acc[m][n][j];
        pp += __shfl_xor(pp, 1);
        pp += __shfl_xor(pp, 2);
        pp += __shfl_xor(pp, 4);
        pp += __shfl_xor(pp, 8);
        if (lq == 0) ssq[lr][wn] = pp;
      }
    asm volatile("" ::: "memory");
    __builtin_amdgcn_s_barrier();
    const int hh = wn >> 1;
    float wv[4];
#pragma unroll
    for (int n = 0; n < 4; ++n) wv[n] = wvec[(wn * 64 + n * 16 + lq) & 127];
#pragma unroll
    for (int m = 0; m < 8; ++m)
#pragma unroll
      for (int j = 0; j < 4; ++j) {
        int lr = wm * 128 + m * 16 + lk * 4 + j;
        float ss = ssq[lr][hh * 2] + ssq[lr][hh * 2 + 1];
        float rs = rsqrtf(ss * (1.0f / 128.0f) + 1e-5f) *
                   (0.08838834764831845f * 1.4426950408889634f);
        f16* dst = Ch + (size_t)(brow + lr) * N + bcol + wn * 64 + lq;
#pragma unroll
        for (int n = 0; n < 4; ++n) dst[n * 16] = (f16)(acc[m][n][j] * rs * wv[n]);
      }
  } else {
    // EPI==2: KV path.  rows r = b*1601+s (M=6404); K half: RMS -> Kf; V half -> Vtf^T
    const bool isK = (bcol < 1024);
    __shared__ float ssq[256][4];
    if (isK) {
#pragma unroll
      for (int m = 0; m < 8; ++m)
#pragma unroll
        for (int j = 0; j < 4; ++j) {
          int lr = wm * 128 + m * 16 + lk * 4 + j;
          float pp = 0.f;
#pragma unroll
          for (int n = 0; n < 4; ++n) pp += acc[m][n][j] * acc[m][n][j];
          pp += __shfl_xor(pp, 1);
          pp += __shfl_xor(pp, 2);
          pp += __shfl_xor(pp, 4);
          pp += __shfl_xor(pp, 8);
          if (lq == 0) ssq[lr][wn] = pp;
        }
      asm volatile("" ::: "memory");
      __builtin_amdgcn_s_barrier();
    }
    const int hh = wn >> 1;
    float wv[4];
    if (isK) {
#pragma unroll
      for (int n = 0; n < 4; ++n) wv[n] = wvec[(wn * 64 + n * 16 + lq) & 127];
    }
#pragma unroll
    for (int m = 0; m < 8; ++m) {
#pragma unroll
      for (int j = 0; j < 4; ++j) {
        int lr = wm * 128 + m * 16 + lk * 4 + j;
        int r = brow + lr;
        if (r >= M) continue;
        unsigned bb = (unsigned)r / 1601u;
        unsigned s = (unsigned)r - bb * 1601u;
        if (isK) {
          float ss = ssq[lr][hh * 2] + ssq[lr][hh * 2 + 1];
          float rs = rsqrtf(ss * (1.0f / 128.0f) + 1e-5f);
#pragma unroll
          for (int n = 0; n < 4; ++n) {
            int col = wn * 64 + n * 16 + lq;
            int kvh = (bcol + col) >> 7;
            int d = col & 127;
            Ch[((size_t)(bb * 8 + kvh) * 1664 + s) * 128 + d] =
                (f16)(acc[m][n][j] * rs * wv[n]);
          }
        } else {
#pragma unroll
          for (int n = 0; n < 4; ++n) {
            int col = bcol - 1024 + wn * 64 + n * 16 + lq;
            int kvh = col >> 7;
            int d = col & 127;
            Vtf[((size_t)(bb * 8 + kvh) * 128 + d) * 1664 + s] = (f16)acc[m][n][j];
          }
        }
      }
    }
  }
}

// ---------------------------------------------------------------- flash attention
// 4 waves x 32 q rows, KVBLK=64, SINGLE-buffered K and V: LDS 48 KB (K 16 +
// V^T 16 + P 16) -> 3 blocks/CU = 12 waves/CU (1.5x r13's 8).  2 barriers/tile
// with rotated handshake; every vmcnt(0) drains loads issued ~1 phase earlier:
//   QK(t) -> vmcnt(0)[V(t), covered by QK] -> bar -> stageK(t+1)
//   -> SM+PV(t) -> vmcnt(0)[K(t+1), covered by SM+PV] -> bar -> stageV(t+1)
// Buffer overwrites sit immediately after the barrier retiring all reads.
// STATIC-MAX softmax (|logit| <= 16.33 bounded by RMS norms; -8 in C-init).
// P swizzle: write swzW = lk<<5 (bijective in lk); read same function of row.
__global__ __launch_bounds__(256, 3) void attn_kernel(const f16* __restrict__ Qf,
                                                      const f16* __restrict__ Kf,
                                                      const f16* __restrict__ Vtf,
                                                      f16* __restrict__ Oa) {
  __shared__ f16 Ksm[64][128];   // 16 KB single, 256 B rows, XOR-swizzled
  __shared__ f16 Vsm[128][64];   // 16 KB single, V^T [d][kv], swizzled
  __shared__ f16 Psm[4][32][64]; // 16 KB per-wave P
  const int p = blockIdx.x;              // 0..1023
  const int L = (p & 7) * 128 + (p >> 3);
  const int qt = L & 7, h = (L >> 3) & 31, b = L >> 8;
  const int kvh = h >> 2;  // G = 4
  const int tid = threadIdx.x;
  const int l = tid & 63, w = tid >> 6;  // 4 waves
  const int lq = l & 15, lk = l >> 4;

  // Q fragments: wave w owns 32 q rows (qt*128 + w*32 ..)
  f16x8 qreg[2][4];
  const f16* Qbase = Qf + ((size_t)(b * 1024 + qt * 128 + w * 32)) * 4096 + h * 128;
#pragma unroll
  for (int qm = 0; qm < 2; ++qm)
#pragma unroll
    for (int ks = 0; ks < 4; ++ks)
      qreg[qm][ks] = *reinterpret_cast<const f16x8*>(
          Qbase + (size_t)(qm * 16 + lq) * 4096 + ks * 32 + lk * 8);

  const f16* Kb = Kf + (size_t)(b * 8 + kvh) * (1664 * 128);
  const f16* Vb = Vtf + (size_t)(b * 8 + kvh) * (128 * 1664);

  f32x4 o[2][8];
  f32x4 zf = {0.f, 0.f, 0.f, 0.f};
  f32x4 neg8 = {-8.f, -8.f, -8.f, -8.f};
#pragma unroll
  for (int qm = 0; qm < 2; ++qm)
#pragma unroll
    for (int dn = 0; dn < 8; ++dn) o[qm][dn] = zf;
  float lrow[2][4];
#pragma unroll
  for (int qm = 0; qm < 2; ++qm)
#pragma unroll
    for (int j = 0; j < 4; ++j) lrow[qm][j] = 0.f;

  char* Pw = (char*)(&Psm[w][0][0]);   // 32 rows x 128 B
  const int swzR = (lq & 7) << 4;      // K/V read swizzle

  auto stageK = [&](int t) {  // 16 KB over 4 waves: 4 issues, 4 rows each
#pragma unroll
    for (int i = 0; i < 4; ++i) {
      int row = w * 16 + i * 4 + lk;
      int cb = (lq * 16) ^ ((row & 7) << 4);
      gload_lds16(Kb + (size_t)(t * 64 + row) * 128 + (cb >> 1),
                  (char*)(&Ksm[0][0]) + w * 4096 + i * 1024);
    }
  };
  auto stageV = [&](int t) {  // 16 KB over 4 waves: 4 issues, 8 rows each
#pragma unroll
    for (int i = 0; i < 4; ++i) {
      int r = w * 32 + i * 8 + (l >> 3);
      int cb = ((l & 7) * 16) ^ ((r & 7) << 4);
      gload_lds16(Vb + (size_t)r * 1664 + t * 64 + (cb >> 1),
                  (char*)(&Vsm[0][0]) + w * 4096 + i * 1024);
    }
  };

  // prologue: tile 0 fully staged
  stageK(0);
  stageV(0);
  asm volatile("s_waitcnt vmcnt(0)" ::: "memory");
  __builtin_amdgcn_s_barrier();

  for (int t = 0; t < 26; ++t) {
    // ---- S = Q K^T - 8 (fp32 accum, static-max offset in C-init)
    f32x4 s[2][4];
#pragma unroll
    for (int qm = 0; qm < 2; ++qm)
#pragma unroll
      for (int kn = 0; kn < 4; ++kn) s[qm][kn] = neg8;
    __builtin_amdgcn_s_setprio(1);
#pragma unroll
    for (int ks = 0; ks < 4; ++ks) {
      f16x8 bf[4];
#pragma unroll
      for (int kn = 0; kn < 4; ++kn)
        bf[kn] = *reinterpret_cast<const f16x8*>(
            (char*)(&Ksm[0][0]) + (kn * 16 + lq) * 256 + ((ks * 64 + lk * 16) ^ swzR));
#pragma unroll
      for (int qm = 0; qm < 2; ++qm)
#pragma unroll
        for (int kn = 0; kn < 4; ++kn)
          s[qm][kn] = __builtin_amdgcn_mfma_f32_16x16x32_f16(qreg[qm][ks], bf[kn], s[qm][kn], 0, 0, 0);
    }
    __builtin_amdgcn_s_setprio(0);

    // ---- handshake 1: own V(t) loads (issued end of t-1) drained, then fence;
    // after the barrier Ksm is reusable for staging K(t+1).
    asm volatile("s_waitcnt vmcnt(0)" ::: "memory");
    __builtin_amdgcn_s_barrier();
    if (t < 25) stageK(t + 1);   // into Ksm (all QK(t) reads retired)

    // ---- mask tail (valid kv < 1601; tile 25 covers 1600..1663 -> local < 1)
    if (t == 25) {
#pragma unroll
      for (int kn = 0; kn < 4; ++kn) {
        bool valid = (kn * 16 + lq) < 1;
#pragma unroll
        for (int qm = 0; qm < 2; ++qm)
#pragma unroll
          for (int j = 0; j < 4; ++j) s[qm][kn][j] = valid ? s[qm][kn][j] : -1e30f;
      }
    }

    // ---- P = 2^s; per-lane partial sums; P write (conflict-free swizzle)
#pragma unroll
    for (int qm = 0; qm < 2; ++qm) {
#pragma unroll
      for (int j = 0; j < 4; ++j) {
        float rsum = 0.f;
#pragma unroll
        for (int kn = 0; kn < 4; ++kn) {
          float pv = exp2f(s[qm][kn][j]);
          s[qm][kn][j] = pv;
          rsum += pv;
        }
        lrow[qm][j] += rsum;
        int prow = qm * 16 + lk * 4 + j;
        int swzW = lk << 5;
#pragma unroll
        for (int kn = 0; kn < 4; ++kn)
          *reinterpret_cast<f16*>(Pw + prow * 128 + (((kn * 16 + lq) * 2) ^ swzW)) =
              (f16)s[qm][kn][j];
      }
    }

    // ---- O += P V  (Vsm valid since prologue / previous handshake 2)
    __builtin_amdgcn_s_setprio(1);
#pragma unroll
    for (int c = 0; c < 2; ++c) {
      f16x8 pa[2];
#pragma unroll
      for (int qm = 0; qm < 2; ++qm) {
        int prow = qm * 16 + lq;
        pa[qm] = *reinterpret_cast<const f16x8*>(
            Pw + prow * 128 + ((c * 64 + lk * 16) ^ (((lq >> 2) & 3) << 5)));
      }
      f16x8 vb[8];
#pragma unroll
      for (int dn = 0; dn < 8; ++dn)
        vb[dn] = *reinterpret_cast<const f16x8*>(
            (char*)(&Vsm[0][0]) + (dn * 16 + lq) * 128 + ((c * 64 + lk * 16) ^ swzR));
#pragma unroll
      for (int qm = 0; qm < 2; ++qm)
#pragma unroll
        for (int dn = 0; dn < 8; ++dn)
          o[qm][dn] = __builtin_amdgcn_mfma_f32_16x16x32_f16(pa[qm], vb[dn], o[qm][dn], 0, 0, 0);
    }
    __builtin_amdgcn_s_setprio(0);

    // ---- handshake 2: own K(t+1) loads (issued after handshake 1) drained,
    // then fence; after the barrier Vsm is reusable for staging V(t+1).
    asm volatile("s_waitcnt vmcnt(0)" ::: "memory");
    __builtin_amdgcn_s_barrier();
    if (t < 25) stageV(t + 1);   // into Vsm (all PV(t) reads retired)
  }

  // ---- epilogue: reduce lrow partials across the 16-lane row group, then O/l
#pragma unroll
  for (int qm = 0; qm < 2; ++qm) {
#pragma unroll
    for (int j = 0; j < 4; ++j) {
      float fl = lrow[qm][j];
      fl += __shfl_xor(fl, 1);
      fl += __shfl_xor(fl, 2);
      fl += __shfl_xor(fl, 4);
      fl += __shfl_xor(fl, 8);
      float il = 1.0f / fl;
      int token = b * 1024 + qt * 128 + w * 32 + qm * 16 + lk * 4 + j;
      f16* dst = Oa + (size_t)token * 4096 + h * 128;
#pragma unroll
      for (int dn = 0; dn < 8; ++dn) dst[dn * 16 + lq] = (f16)(o[qm][dn][j] * il);
    }
  }
}

// ---------------------------------------------------------------- launch
extern "C" void kernel_launch(void* const* d_in, const int* in_sizes, int n_in,
                              void* d_out, int out_size, void* d_ws, size_t ws_size,
                              hipStream_t stream) {
  const float* hidden = (const float*)d_in[0];  // [4,1024,4096]
  const float* cross  = (const float*)d_in[1];  // [4,1601,4096]
  const float* wqkv   = (const float*)d_in[2];  // [6144,4096]
  const float* wo     = (const float*)d_in[3];  // [4096,4096]
  const float* qw     = (const float*)d_in[4];  // [128]
  const float* kw     = (const float*)d_in[5];  // [128]

  char* ws = (char*)d_ws;
  f16* hidden_h = (f16*)(ws + 0);            // 33.55 MB -> attn_h after Q-proj
  f16* attn_h   = hidden_h;
  f16* wqkv_h = (f16*)(ws + 33554432);       // 50.33 MB
  f16* cross_h = (f16*)(ws + 83886080);      // 52.46 MB (-> wo_h in fallback)
  f16* k_h  = (f16*)(ws + 136347648);        // 13.63 MB
  f16* vt_h = (f16*)(ws + 136347648 + 13631488);  // 13.63 MB
  f16* q_h = (f16*)d_out;  // consumed by attn before O-proj overwrites d_out

  // wo_h: own region at +163.6 MB when workspace allows (fuses its convert
  // into cvtzero, before KV-proj); else fallback = r13 path (convert after
  // KV-proj into the dead cross_h region).
  const bool fuse_wo = (ws_size >= (size_t)197165056);
  f16* wo_h = fuse_wo ? (f16*)(ws + 163610624) : (f16*)(ws + 83886080);

  // 1) fused converts (hidden, cross, wqkv [, wo]) + zero-fill of K/Vt pads
  cvtzero_kernel<<<2048, 256, 0, stream>>>(hidden, hidden_h, cross, cross_h,
                                           wqkv, wqkv_h, wo, wo_h,
                                           fuse_wo ? 4194304 : 0,
                                           (float4*)(ws + 136347648));
  // 2) KV projection with fused K-RMS + V-transpose epilogue
  gemm256<true, 2><<<dim3(8, 26), 512, 0, stream>>>(
      cross_h, wqkv_h + (size_t)4096 * 4096, nullptr, k_h, kw, vt_h, 6404, 2048, 4096);
  // 3) wo convert fallback (only when not fused)
  if (!fuse_wo)
    cvt_kernel<<<2048, 256, 0, stream>>>(wo, wo_h, 16777216 / 4);
  // 4) Q projection with fused RMS-norm (+scale*log2e) -> f16 q_h (in d_out)
  gemm256<false, 1><<<dim3(16, 16), 512, 0, stream>>>(
      hidden_h, wqkv_h, nullptr, q_h, qw, nullptr, 4096, 4096, 4096);
  // 5) attention (4-wave blocks, 48 KB LDS, 3 blocks/CU)
  attn_kernel<<<1024, 256, 0, stream>>>(q_h, k_h, vt_h, attn_h);
  // 6) output projection -> d_out
  gemm256<false, 0><<<dim3(16, 16), 512, 0, stream>>>(
      attn_h, wo_h, (float*)d_out, nullptr, nullptr, nullptr, 4096, 4096, 4096);
}

// Round 15
// 617.012 us; speedup vs baseline: 1.0939x; 1.0939x over previous
//
#include <hip/hip_runtime.h>
#include <cstdint>
#include <math.h>

typedef _Float16 f16;
typedef __attribute__((ext_vector_type(4))) _Float16 f16x4;
typedef __attribute__((ext_vector_type(8))) _Float16 f16x8;
typedef __attribute__((ext_vector_type(4))) float f32x4;

// ---------------------------------------------------------------- helpers
__device__ inline void gload_lds16(const void* g, void* l) {
  auto gp = reinterpret_cast<const __attribute__((address_space(1))) uint32_t*>(
      reinterpret_cast<uintptr_t>(g));
  auto lp = reinterpret_cast<__attribute__((address_space(3))) uint32_t*>(
      reinterpret_cast<uintptr_t>(l));
  __builtin_amdgcn_global_load_lds(gp, lp, 16 /*bytes*/, 0, 0);
}

// ---------------------------------------------------------------- fused fp32->f16 converts + zero-fill
// Ranges: hidden (4194304 f4) | cross (6557696) | wqkv (6291456) | wo (nwo: 0 or
// 4194304) | zero K/Vt (1703936 x16B)
__global__ __launch_bounds__(256) void cvtzero_kernel(const float* __restrict__ s0, f16* __restrict__ d0,
                                                      const float* __restrict__ s1, f16* __restrict__ d1,
                                                      const float* __restrict__ s2, f16* __restrict__ d2,
                                                      const float* __restrict__ s3, f16* __restrict__ d3,
                                                      int nwo,
                                                      float4* __restrict__ z) {
  int idx = blockIdx.x * blockDim.x + threadIdx.x;
  int stride = gridDim.x * blockDim.x;
  const int nz0 = 17043456 + nwo;
  const int total = nz0 + 1703936;
  for (int i = idx; i < total; i += stride) {
    const float* src; f16* dst; int k;
    if (i < 4194304) { src = s0; dst = d0; k = i; }
    else if (i < 10752000) { src = s1; dst = d1; k = i - 4194304; }
    else if (i < 17043456) { src = s2; dst = d2; k = i - 10752000; }
    else if (i < nz0) { src = s3; dst = d3; k = i - 17043456; }
    else { float4 zr = {0.f, 0.f, 0.f, 0.f}; z[i - nz0] = zr; continue; }
    float4 v = reinterpret_cast<const float4*>(src)[k];
    f16x4 h;
    h.x = (f16)v.x; h.y = (f16)v.y; h.z = (f16)v.z; h.w = (f16)v.w;
    reinterpret_cast<f16x4*>(dst)[k] = h;
  }
}

// ---------------------------------------------------------------- plain fp32 -> f16 convert (wo fallback)
__global__ __launch_bounds__(256) void cvt_kernel(const float* __restrict__ src,
                                                  f16* __restrict__ dst, int n4) {
  int idx = blockIdx.x * blockDim.x + threadIdx.x;
  int stride = gridDim.x * blockDim.x;
  for (int i = idx; i < n4; i += stride) {
    float4 v = reinterpret_cast<const float4*>(src)[i];
    f16x4 h;
    h.x = (f16)v.x; h.y = (f16)v.y; h.z = (f16)v.z; h.w = (f16)v.w;
    reinterpret_cast<f16x4*>(dst)[i] = h;
  }
}

// ---------------------------------------------------------------- 256x256 GEMM, m201-style 4-phase
// (r12 state -- verified) 512 thr / 8 waves (2M x 4N), per-wave 128x64, BK=64,
// LDS 128 KB dbuf, ONE barrier/phase with hoisted ds_reads + staging, counted
// vmcnt(2) at tile entry, setprio around MFMA clusters.
// EPI==0: fp32 C.  EPI==1: per-128-col RMS -> f16 Ch (Q path, scale*log2e).
// EPI==2: KV path (K-half: RMS -> Kf; V-half: transpose -> Vtf).
template <bool MB, int EPI>
__global__ __launch_bounds__(512, 2) void gemm256(const f16* __restrict__ A,
                                                  const f16* __restrict__ Bw,
                                                  float* __restrict__ C,
                                                  f16* __restrict__ Ch,
                                                  const float* __restrict__ wvec,
                                                  f16* __restrict__ Vtf,
                                                  int M, int N, int K) {
  __shared__ f16 As[2][256][64];
  __shared__ f16 Bs[2][256][64];
  const int tid = threadIdx.x;
  const int l = tid & 63, w = tid >> 6;  // 8 waves
  const int lq = l & 15, lk = l >> 4;
  const int wm = w >> 2, wn = w & 3;     // 2M x 4N wave grid
  const int nwg = gridDim.x * gridDim.y;
  const int p = blockIdx.y * gridDim.x + blockIdx.x;
  const int L = (p & 7) * (nwg >> 3) + (p >> 3);
  const int bx = L % gridDim.x, by = L / gridDim.x;
  const int brow = by * 256, bcol = bx * 256;
  const int KT = K >> 6;

  const int srow8 = w * 8 + (l >> 3);            // + i*64
  const int scol  = ((l & 7) ^ (l >> 3)) * 8;    // pre-swizzled source col (f16)
  const int swz   = (lq & 7) << 4;               // read-side XOR

  f32x4 acc[8][4];
  f32x4 zf = {0.f, 0.f, 0.f, 0.f};
#pragma unroll
  for (int m = 0; m < 8; ++m)
#pragma unroll
    for (int n = 0; n < 4; ++n) acc[m][n] = zf;

  auto stageA = [&](int kt, int buf, int i) {
    int ra = brow + i * 64 + srow8;
    if (MB) ra = (ra < M) ? ra : (M - 1);
    gload_lds16(A + (size_t)ra * K + kt * 64 + scol,
                (char*)(&As[buf][0][0]) + i * 8192 + w * 1024);
  };
  auto stageB = [&](int kt, int buf, int i) {
    int rb = bcol + i * 64 + srow8;
    gload_lds16(Bw + (size_t)rb * K + kt * 64 + scol,
                (char*)(&Bs[buf][0][0]) + i * 8192 + w * 1024);
  };
  auto ldA = [&](int buf, int m, int kk) -> f16x8 {
    int r = wm * 128 + m * 16 + lq;
    return *reinterpret_cast<const f16x8*>(
        (char*)(&As[buf][0][0]) + r * 128 + ((kk * 64 + lk * 16) ^ swz));
  };
  auto ldB = [&](int buf, int n, int kk) -> f16x8 {
    int r = wn * 64 + n * 16 + lq;
    return *reinterpret_cast<const f16x8*>(
        (char*)(&Bs[buf][0][0]) + r * 128 + ((kk * 64 + lk * 16) ^ swz));
  };

  // prologue: stage tile 0 (8 issues)
#pragma unroll
  for (int i = 0; i < 4; ++i) stageA(0, 0, i);
#pragma unroll
  for (int i = 0; i < 4; ++i) stageB(0, 0, i);

  f16x8 avA[4][2], avB[4][2], bvA[2][2], bvB[2][2];
  for (int t = 0; t < KT; ++t) {
    const int buf = t & 1, nbuf = buf ^ 1;
    const bool pf = (t + 1 < KT);

    // ---- tile entry: 2 stages ahead, then wait for tile-t's 8
    if (pf) {
      stageA(t + 1, nbuf, 0); stageA(t + 1, nbuf, 1);
      asm volatile("s_waitcnt vmcnt(2)" ::: "memory");
    } else {
      asm volatile("s_waitcnt vmcnt(0)" ::: "memory");
    }
    __builtin_amdgcn_s_barrier();

    // ---- phase 0: (m0-3 x n0-1)
#pragma unroll
    for (int mm = 0; mm < 4; ++mm)
#pragma unroll
      for (int kk = 0; kk < 2; ++kk) avA[mm][kk] = ldA(buf, mm, kk);
#pragma unroll
    for (int nn = 0; nn < 2; ++nn)
#pragma unroll
      for (int kk = 0; kk < 2; ++kk) bvA[nn][kk] = ldB(buf, nn, kk);
    __builtin_amdgcn_s_setprio(1);
#pragma unroll
    for (int mm = 0; mm < 4; ++mm)
#pragma unroll
      for (int nn = 0; nn < 2; ++nn)
#pragma unroll
        for (int kk = 0; kk < 2; ++kk)
          acc[mm][nn] = __builtin_amdgcn_mfma_f32_16x16x32_f16(avA[mm][kk], bvA[nn][kk], acc[mm][nn], 0, 0, 0);
    __builtin_amdgcn_s_setprio(0);
#pragma unroll
    for (int mm = 0; mm < 4; ++mm)
#pragma unroll
      for (int kk = 0; kk < 2; ++kk) avB[mm][kk] = ldA(buf, 4 + mm, kk);
    if (pf) { stageA(t + 1, nbuf, 2); stageA(t + 1, nbuf, 3); }
    asm volatile("" ::: "memory");
    __builtin_amdgcn_s_barrier();

    // ---- phase 1: (m4-7 x n0-1)
    __builtin_amdgcn_s_setprio(1);
#pragma unroll
    for (int mm = 0; mm < 4; ++mm)
#pragma unroll
      for (int nn = 0; nn < 2; ++nn)
#pragma unroll
        for (int kk = 0; kk < 2; ++kk)
          acc[4 + mm][nn] = __builtin_amdgcn_mfma_f32_16x16x32_f16(avB[mm][kk], bvA[nn][kk], acc[4 + mm][nn], 0, 0, 0);
    __builtin_amdgcn_s_setprio(0);
#pragma unroll
    for (int nn = 0; nn < 2; ++nn)
#pragma unroll
      for (int kk = 0; kk < 2; ++kk) bvB[nn][kk] = ldB(buf, 2 + nn, kk);
    if (pf) { stageB(t + 1, nbuf, 0); stageB(t + 1, nbuf, 1); }
    asm volatile("" ::: "memory");
    __builtin_amdgcn_s_barrier();

    // ---- phase 2: (m4-7 x n2-3)
    __builtin_amdgcn_s_setprio(1);
#pragma unroll
    for (int mm = 0; mm < 4; ++mm)
#pragma unroll
      for (int nn = 0; nn < 2; ++nn)
#pragma unroll
        for (int kk = 0; kk < 2; ++kk)
          acc[4 + mm][2 + nn] = __builtin_amdgcn_mfma_f32_16x16x32_f16(avB[mm][kk], bvB[nn][kk], acc[4 + mm][2 + nn], 0, 0, 0);
    __builtin_amdgcn_s_setprio(0);
#pragma unroll
    for (int mm = 0; mm < 4; ++mm)
#pragma unroll
      for (int kk = 0; kk < 2; ++kk) avA[mm][kk] = ldA(buf, mm, kk);
    if (pf) { stageB(t + 1, nbuf, 2); stageB(t + 1, nbuf, 3); }
    asm volatile("" ::: "memory");
    __builtin_amdgcn_s_barrier();

    // ---- phase 3: (m0-3 x n2-3)
    __builtin_amdgcn_s_setprio(1);
#pragma unroll
    for (int mm = 0; mm < 4; ++mm)
#pragma unroll
      for (int nn = 0; nn < 2; ++nn)
#pragma unroll
        for (int kk = 0; kk < 2; ++kk)
          acc[mm][2 + nn] = __builtin_amdgcn_mfma_f32_16x16x32_f16(avA[mm][kk], bvB[nn][kk], acc[mm][2 + nn], 0, 0, 0);
    __builtin_amdgcn_s_setprio(0);
  }

  if (EPI == 0) {
#pragma unroll
    for (int m = 0; m < 8; ++m) {
#pragma unroll
      for (int j = 0; j < 4; ++j) {
        int row = brow + wm * 128 + m * 16 + lk * 4 + j;
        if (MB && row >= M) continue;
        float* dst = C + (size_t)row * N + bcol + wn * 64 + lq;
#pragma unroll
        for (int n = 0; n < 4; ++n) dst[n * 16] = acc[m][n][j];
      }
    }
  } else if (EPI == 1) {
    __shared__ float ssq[256][4];
#pragma unroll
    for (int m = 0; m < 8; ++m)
#pragma unroll
      for (int j = 0; j < 4; ++j) {
        int lr = wm * 128 + m * 16 + lk * 4 + j;
        float pp = 0.f;
#pragma unroll
        for (int n = 0; n < 4; ++n) pp += acc[m][n][j] * acc[m][n][j];
        pp += __shfl_xor(pp, 1);
        pp += __shfl_xor(pp, 2);
        pp += __shfl_xor(pp, 4);
        pp += __shfl_xor(pp, 8);
        if (lq == 0) ssq[lr][wn] = pp;
      }
    asm volatile("" ::: "memory");
    __builtin_amdgcn_s_barrier();
    const int hh = wn >> 1;
    float wv[4];
#pragma unroll
    for (int n = 0; n < 4; ++n) wv[n] = wvec[(wn * 64 + n * 16 + lq) & 127];
#pragma unroll
    for (int m = 0; m < 8; ++m)
#pragma unroll
      for (int j = 0; j < 4; ++j) {
        int lr = wm * 128 + m * 16 + lk * 4 + j;
        float ss = ssq[lr][hh * 2] + ssq[lr][hh * 2 + 1];
        float rs = rsqrtf(ss * (1.0f / 128.0f) + 1e-5f) *
                   (0.08838834764831845f * 1.4426950408889634f);
        f16* dst = Ch + (size_t)(brow + lr) * N + bcol + wn * 64 + lq;
#pragma unroll
        for (int n = 0; n < 4; ++n) dst[n * 16] = (f16)(acc[m][n][j] * rs * wv[n]);
      }
  } else {
    // EPI==2: KV path.  rows r = b*1601+s (M=6404); K half: RMS -> Kf; V half -> Vtf^T
    const bool isK = (bcol < 1024);
    __shared__ float ssq[256][4];
    if (isK) {
#pragma unroll
      for (int m = 0; m < 8; ++m)
#pragma unroll
        for (int j = 0; j < 4; ++j) {
          int lr = wm * 128 + m * 16 + lk * 4 + j;
          float pp = 0.f;
#pragma unroll
          for (int n = 0; n < 4; ++n) pp += acc[m][n][j] * acc[m][n][j];
          pp += __shfl_xor(pp, 1);
          pp += __shfl_xor(pp, 2);
          pp += __shfl_xor(pp, 4);
          pp += __shfl_xor(pp, 8);
          if (lq == 0) ssq[lr][wn] = pp;
        }
      asm volatile("" ::: "memory");
      __builtin_amdgcn_s_barrier();
    }
    const int hh = wn >> 1;
    float wv[4];
    if (isK) {
#pragma unroll
      for (int n = 0; n < 4; ++n) wv[n] = wvec[(wn * 64 + n * 16 + lq) & 127];
    }
#pragma unroll
    for (int m = 0; m < 8; ++m) {
#pragma unroll
      for (int j = 0; j < 4; ++j) {
        int lr = wm * 128 + m * 16 + lk * 4 + j;
        int r = brow + lr;
        if (r >= M) continue;
        unsigned bb = (unsigned)r / 1601u;
        unsigned s = (unsigned)r - bb * 1601u;
        if (isK) {
          float ss = ssq[lr][hh * 2] + ssq[lr][hh * 2 + 1];
          float rs = rsqrtf(ss * (1.0f / 128.0f) + 1e-5f);
#pragma unroll
          for (int n = 0; n < 4; ++n) {
            int col = wn * 64 + n * 16 + lq;
            int kvh = (bcol + col) >> 7;
            int d = col & 127;
            Ch[((size_t)(bb * 8 + kvh) * 1664 + s) * 128 + d] =
                (f16)(acc[m][n][j] * rs * wv[n]);
          }
        } else {
#pragma unroll
          for (int n = 0; n < 4; ++n) {
            int col = bcol - 1024 + wn * 64 + n * 16 + lq;
            int kvh = col >> 7;
            int d = col & 127;
            Vtf[((size_t)(bb * 8 + kvh) * 128 + d) * 1664 + s] = (f16)acc[m][n][j];
          }
        }
      }
    }
  }
}

// ---------------------------------------------------------------- flash attention
// 8 waves x 16 q rows (512-thr, QBLK=128), KVBLK=64, K/V DOUBLE-buffered (r11
// shape: 41% occupancy) + r13's conflict-free P swizzle.  LDS 80 KB, 2 blocks/CU
// = 16 waves/CU.  Counted vmcnt(4) keeps tile t+1's staging in flight (r14's
// single-buffer vmcnt(0)-drain experiment regressed: drains serialize the block).
// STATIC-MAX softmax (|logit| <= 16.33 bounded by RMS norms; -8 in C-init).
// P swizzle: write swzW = lk<<5 (bijective in lk -> 32 banks, 2 adjacent-byte
// lanes each = free); read ((lq>>2)&3)<<5 (same function of row; 8 lanes/quad
// = b128 minimum).  Old ((prow&7)<<4) was 4-way (13.2M conflict cycles).
__global__ __launch_bounds__(512, 4) void attn_kernel(const f16* __restrict__ Qf,
                                                      const f16* __restrict__ Kf,
                                                      const f16* __restrict__ Vtf,
                                                      f16* __restrict__ Oa) {
  __shared__ f16 Ksm[2][64][128];  // 32 KB dbuf, 256 B rows, XOR-swizzled
  __shared__ f16 Vsm[2][128][64];  // 32 KB dbuf, V^T [d][kv], swizzled
  __shared__ f16 Psm[8][16][64];   // 16 KB per-wave P
  const int p = blockIdx.x;              // 0..1023
  const int L = (p & 7) * 128 + (p >> 3);
  const int qt = L & 7, h = (L >> 3) & 31, b = L >> 8;
  const int kvh = h >> 2;  // G = 4
  const int tid = threadIdx.x;
  const int l = tid & 63, w = tid >> 6;  // 8 waves
  const int lq = l & 15, lk = l >> 4;

  f16x8 qreg[4];
  const f16* Qbase = Qf + ((size_t)(b * 1024 + qt * 128 + w * 16)) * 4096 + h * 128;
#pragma unroll
  for (int ks = 0; ks < 4; ++ks)
    qreg[ks] = *reinterpret_cast<const f16x8*>(
        Qbase + (size_t)lq * 4096 + ks * 32 + lk * 8);

  const f16* Kb = Kf + (size_t)(b * 8 + kvh) * (1664 * 128);
  const f16* Vb = Vtf + (size_t)(b * 8 + kvh) * (128 * 1664);

  f32x4 o[8];
  f32x4 zf = {0.f, 0.f, 0.f, 0.f};
  f32x4 neg8 = {-8.f, -8.f, -8.f, -8.f};
#pragma unroll
  for (int dn = 0; dn < 8; ++dn) o[dn] = zf;
  float lrow[4];  // per-lane partial row sums, reduced once in epilogue
#pragma unroll
  for (int j = 0; j < 4; ++j) lrow[j] = 0.f;

  char* Pw = (char*)(&Psm[w][0][0]);
  const int swzR = (lq & 7) << 4;      // K/V read swizzle

  auto stageK = [&](int t, int buf) {  // 16 KB over 8 waves: 2 issues/wave
#pragma unroll
    for (int i = 0; i < 2; ++i) {
      int row = w * 8 + i * 4 + lk;
      int cb = (lq * 16) ^ ((row & 7) << 4);
      gload_lds16(Kb + (size_t)(t * 64 + row) * 128 + (cb >> 1),
                  (char*)(&Ksm[buf][0][0]) + w * 2048 + i * 1024);
    }
  };
  auto stageV = [&](int t, int buf) {  // 16 KB over 8 waves: 2 issues/wave
#pragma unroll
    for (int i = 0; i < 2; ++i) {
      int r = w * 16 + i * 8 + (l >> 3);
      int cb = ((l & 7) * 16) ^ ((r & 7) << 4);
      gload_lds16(Vb + (size_t)r * 1664 + t * 64 + (cb >> 1),
                  (char*)(&Vsm[buf][0][0]) + w * 2048 + i * 1024);
    }
  };

  stageK(0, 0);
  stageV(0, 0);
  int cur = 0;
  for (int t = 0; t < 26; ++t) {
    if (t < 25) {
      stageK(t + 1, cur ^ 1);
      stageV(t + 1, cur ^ 1);
      asm volatile("s_waitcnt vmcnt(4)" ::: "memory");
    } else {
      asm volatile("s_waitcnt vmcnt(0)" ::: "memory");
    }
    __builtin_amdgcn_s_barrier();

    // ---- S = Q K^T - 8 (fp32 accum, static-max offset in C-init)
    f32x4 s[4];
#pragma unroll
    for (int kn = 0; kn < 4; ++kn) s[kn] = neg8;
    __builtin_amdgcn_s_setprio(1);
#pragma unroll
    for (int ks = 0; ks < 4; ++ks) {
      f16x8 bf[4];
#pragma unroll
      for (int kn = 0; kn < 4; ++kn)
        bf[kn] = *reinterpret_cast<const f16x8*>(
            (char*)(&Ksm[cur][0][0]) + (kn * 16 + lq) * 256 + ((ks * 64 + lk * 16) ^ swzR));
#pragma unroll
      for (int kn = 0; kn < 4; ++kn)
        s[kn] = __builtin_amdgcn_mfma_f32_16x16x32_f16(qreg[ks], bf[kn], s[kn], 0, 0, 0);
    }
    __builtin_amdgcn_s_setprio(0);

    // ---- mask tail (valid kv < 1601; tile 25 covers 1600..1663 -> local < 1)
    if (t == 25) {
#pragma unroll
      for (int kn = 0; kn < 4; ++kn) {
        bool valid = (kn * 16 + lq) < 1;
#pragma unroll
        for (int j = 0; j < 4; ++j) s[kn][j] = valid ? s[kn][j] : -1e30f;
      }
    }

    // ---- P = 2^s; per-lane partial sums; P write (conflict-free swizzle)
#pragma unroll
    for (int j = 0; j < 4; ++j) {
      float rsum = 0.f;
#pragma unroll
      for (int kn = 0; kn < 4; ++kn) {
        float pv = exp2f(s[kn][j]);
        s[kn][j] = pv;
        rsum += pv;
      }
      lrow[j] += rsum;
      int prow = lk * 4 + j;
      int swzW = lk << 5;  // = ((prow>>2)&3)<<5, bijective in lk
#pragma unroll
      for (int kn = 0; kn < 4; ++kn)
        *reinterpret_cast<f16*>(Pw + prow * 128 + (((kn * 16 + lq) * 2) ^ swzW)) =
            (f16)s[kn][j];
    }

    // ---- O += P V   (pa read uses same swizzle function of row)
    __builtin_amdgcn_s_setprio(1);
#pragma unroll
    for (int c = 0; c < 2; ++c) {
      f16x8 pa = *reinterpret_cast<const f16x8*>(
          Pw + lq * 128 + ((c * 64 + lk * 16) ^ (((lq >> 2) & 3) << 5)));
      f16x8 vb[8];
#pragma unroll
      for (int dn = 0; dn < 8; ++dn)
        vb[dn] = *reinterpret_cast<const f16x8*>(
            (char*)(&Vsm[cur][0][0]) + (dn * 16 + lq) * 128 + ((c * 64 + lk * 16) ^ swzR));
#pragma unroll
      for (int dn = 0; dn < 8; ++dn)
        o[dn] = __builtin_amdgcn_mfma_f32_16x16x32_f16(pa, vb[dn], o[dn], 0, 0, 0);
    }
    __builtin_amdgcn_s_setprio(0);
    __builtin_amdgcn_s_barrier();
    cur ^= 1;
  }

  // ---- epilogue: reduce lrow partials across the 16-lane row group, then O/l
#pragma unroll
  for (int j = 0; j < 4; ++j) {
    float fl = lrow[j];
    fl += __shfl_xor(fl, 1);
    fl += __shfl_xor(fl, 2);
    fl += __shfl_xor(fl, 4);
    fl += __shfl_xor(fl, 8);
    float il = 1.0f / fl;
    int token = b * 1024 + qt * 128 + w * 16 + lk * 4 + j;
    f16* dst = Oa + (size_t)token * 4096 + h * 128;
#pragma unroll
    for (int dn = 0; dn < 8; ++dn) dst[dn * 16 + lq] = (f16)(o[dn][j] * il);
  }
}

// ---------------------------------------------------------------- launch
extern "C" void kernel_launch(void* const* d_in, const int* in_sizes, int n_in,
                              void* d_out, int out_size, void* d_ws, size_t ws_size,
                              hipStream_t stream) {
  const float* hidden = (const float*)d_in[0];  // [4,1024,4096]
  const float* cross  = (const float*)d_in[1];  // [4,1601,4096]
  const float* wqkv   = (const float*)d_in[2];  // [6144,4096]
  const float* wo     = (const float*)d_in[3];  // [4096,4096]
  const float* qw     = (const float*)d_in[4];  // [128]
  const float* kw     = (const float*)d_in[5];  // [128]

  char* ws = (char*)d_ws;
  f16* hidden_h = (f16*)(ws + 0);            // 33.55 MB -> attn_h after Q-proj
  f16* attn_h   = hidden_h;
  f16* wqkv_h = (f16*)(ws + 33554432);       // 50.33 MB
  f16* cross_h = (f16*)(ws + 83886080);      // 52.46 MB (-> wo_h in fallback)
  f16* k_h  = (f16*)(ws + 136347648);        // 13.63 MB
  f16* vt_h = (f16*)(ws + 136347648 + 13631488);  // 13.63 MB
  f16* q_h = (f16*)d_out;  // consumed by attn before O-proj overwrites d_out

  // wo_h: own region at +163.6 MB when workspace allows (fuses its convert
  // into cvtzero, before KV-proj); else fallback = convert after KV-proj into
  // the dead cross_h region.
  const bool fuse_wo = (ws_size >= (size_t)197165056);
  f16* wo_h = fuse_wo ? (f16*)(ws + 163610624) : (f16*)(ws + 83886080);

  // 1) fused converts (hidden, cross, wqkv [, wo]) + zero-fill of K/Vt pads
  cvtzero_kernel<<<2048, 256, 0, stream>>>(hidden, hidden_h, cross, cross_h,
                                           wqkv, wqkv_h, wo, wo_h,
                                           fuse_wo ? 4194304 : 0,
                                           (float4*)(ws + 136347648));
  // 2) KV projection with fused K-RMS + V-transpose epilogue
  gemm256<true, 2><<<dim3(8, 26), 512, 0, stream>>>(
      cross_h, wqkv_h + (size_t)4096 * 4096, nullptr, k_h, kw, vt_h, 6404, 2048, 4096);
  // 3) wo convert fallback (only when not fused)
  if (!fuse_wo)
    cvt_kernel<<<2048, 256, 0, stream>>>(wo, wo_h, 16777216 / 4);
  // 4) Q projection with fused RMS-norm (+scale*log2e) -> f16 q_h (in d_out)
  gemm256<false, 1><<<dim3(16, 16), 512, 0, stream>>>(
      hidden_h, wqkv_h, nullptr, q_h, qw, nullptr, 4096, 4096, 4096);
  // 5) attention (8-wave blocks, dbuf K/V, conflict-free P swizzle)
  attn_kernel<<<1024, 512, 0, stream>>>(q_h, k_h, vt_h, attn_h);
  // 6) output projection -> d_out
  gemm256<false, 0><<<dim3(16, 16), 512, 0, stream>>>(
      attn_h, wo_h, (float*)d_out, nullptr, nullptr, nullptr, 4096, 4096, 4096);
}

// Round 16
// 607.597 us; speedup vs baseline: 1.1109x; 1.0155x over previous
//
#include <hip/hip_runtime.h>
#include <cstdint>
#include <math.h>

typedef _Float16 f16;
typedef __attribute__((ext_vector_type(4))) _Float16 f16x4;
typedef __attribute__((ext_vector_type(8))) _Float16 f16x8;
typedef __attribute__((ext_vector_type(4))) float f32x4;

// ---------------------------------------------------------------- helpers
__device__ inline void gload_lds16(const void* g, void* l) {
  auto gp = reinterpret_cast<const __attribute__((address_space(1))) uint32_t*>(
      reinterpret_cast<uintptr_t>(g));
  auto lp = reinterpret_cast<__attribute__((address_space(3))) uint32_t*>(
      reinterpret_cast<uintptr_t>(l));
  __builtin_amdgcn_global_load_lds(gp, lp, 16 /*bytes*/, 0, 0);
}

// ---------------------------------------------------------------- fused fp32->f16 converts + zero-fill
// Ranges: hidden (4194304 f4) | cross (6557696) | wqkv (6291456) | wo (nwo: 0 or
// 4194304) | zero K/Vt (1703936 x16B)
__global__ __launch_bounds__(256) void cvtzero_kernel(const float* __restrict__ s0, f16* __restrict__ d0,
                                                      const float* __restrict__ s1, f16* __restrict__ d1,
                                                      const float* __restrict__ s2, f16* __restrict__ d2,
                                                      const float* __restrict__ s3, f16* __restrict__ d3,
                                                      int nwo,
                                                      float4* __restrict__ z) {
  int idx = blockIdx.x * blockDim.x + threadIdx.x;
  int stride = gridDim.x * blockDim.x;
  const int nz0 = 17043456 + nwo;
  const int total = nz0 + 1703936;
  for (int i = idx; i < total; i += stride) {
    const float* src; f16* dst; int k;
    if (i < 4194304) { src = s0; dst = d0; k = i; }
    else if (i < 10752000) { src = s1; dst = d1; k = i - 4194304; }
    else if (i < 17043456) { src = s2; dst = d2; k = i - 10752000; }
    else if (i < nz0) { src = s3; dst = d3; k = i - 17043456; }
    else { float4 zr = {0.f, 0.f, 0.f, 0.f}; z[i - nz0] = zr; continue; }
    float4 v = reinterpret_cast<const float4*>(src)[k];
    f16x4 h;
    h.x = (f16)v.x; h.y = (f16)v.y; h.z = (f16)v.z; h.w = (f16)v.w;
    reinterpret_cast<f16x4*>(dst)[k] = h;
  }
}

// ---------------------------------------------------------------- plain fp32 -> f16 convert (wo fallback)
__global__ __launch_bounds__(256) void cvt_kernel(const float* __restrict__ src,
                                                  f16* __restrict__ dst, int n4) {
  int idx = blockIdx.x * blockDim.x + threadIdx.x;
  int stride = gridDim.x * blockDim.x;
  for (int i = idx; i < n4; i += stride) {
    float4 v = reinterpret_cast<const float4*>(src)[i];
    f16x4 h;
    h.x = (f16)v.x; h.y = (f16)v.y; h.z = (f16)v.z; h.w = (f16)v.w;
    reinterpret_cast<f16x4*>(dst)[i] = h;
  }
}

// ---------------------------------------------------------------- 256x256 GEMM, m201-style 4-phase
// (r12 state -- verified) 512 thr / 8 waves (2M x 4N), per-wave 128x64, BK=64,
// LDS 128 KB dbuf, ONE barrier/phase with hoisted ds_reads + staging, counted
// vmcnt(2) at tile entry, setprio around MFMA clusters.
// EPI==0: fp32 C.  EPI==1: per-128-col RMS -> f16 Ch (Q path, scale*log2e).
// EPI==2: KV path (K-half: RMS -> Kf; V-half: transpose -> Vtf).
template <bool MB, int EPI>
__global__ __launch_bounds__(512, 2) void gemm256(const f16* __restrict__ A,
                                                  const f16* __restrict__ Bw,
                                                  float* __restrict__ C,
                                                  f16* __restrict__ Ch,
                                                  const float* __restrict__ wvec,
                                                  f16* __restrict__ Vtf,
                                                  int M, int N, int K) {
  __shared__ f16 As[2][256][64];
  __shared__ f16 Bs[2][256][64];
  const int tid = threadIdx.x;
  const int l = tid & 63, w = tid >> 6;  // 8 waves
  const int lq = l & 15, lk = l >> 4;
  const int wm = w >> 2, wn = w & 3;     // 2M x 4N wave grid
  const int nwg = gridDim.x * gridDim.y;
  const int p = blockIdx.y * gridDim.x + blockIdx.x;
  const int L = (p & 7) * (nwg >> 3) + (p >> 3);
  const int bx = L % gridDim.x, by = L / gridDim.x;
  const int brow = by * 256, bcol = bx * 256;
  const int KT = K >> 6;

  const int srow8 = w * 8 + (l >> 3);            // + i*64
  const int scol  = ((l & 7) ^ (l >> 3)) * 8;    // pre-swizzled source col (f16)
  const int swz   = (lq & 7) << 4;               // read-side XOR

  f32x4 acc[8][4];
  f32x4 zf = {0.f, 0.f, 0.f, 0.f};
#pragma unroll
  for (int m = 0; m < 8; ++m)
#pragma unroll
    for (int n = 0; n < 4; ++n) acc[m][n] = zf;

  auto stageA = [&](int kt, int buf, int i) {
    int ra = brow + i * 64 + srow8;
    if (MB) ra = (ra < M) ? ra : (M - 1);
    gload_lds16(A + (size_t)ra * K + kt * 64 + scol,
                (char*)(&As[buf][0][0]) + i * 8192 + w * 1024);
  };
  auto stageB = [&](int kt, int buf, int i) {
    int rb = bcol + i * 64 + srow8;
    gload_lds16(Bw + (size_t)rb * K + kt * 64 + scol,
                (char*)(&Bs[buf][0][0]) + i * 8192 + w * 1024);
  };
  auto ldA = [&](int buf, int m, int kk) -> f16x8 {
    int r = wm * 128 + m * 16 + lq;
    return *reinterpret_cast<const f16x8*>(
        (char*)(&As[buf][0][0]) + r * 128 + ((kk * 64 + lk * 16) ^ swz));
  };
  auto ldB = [&](int buf, int n, int kk) -> f16x8 {
    int r = wn * 64 + n * 16 + lq;
    return *reinterpret_cast<const f16x8*>(
        (char*)(&Bs[buf][0][0]) + r * 128 + ((kk * 64 + lk * 16) ^ swz));
  };

  // prologue: stage tile 0 (8 issues)
#pragma unroll
  for (int i = 0; i < 4; ++i) stageA(0, 0, i);
#pragma unroll
  for (int i = 0; i < 4; ++i) stageB(0, 0, i);

  f16x8 avA[4][2], avB[4][2], bvA[2][2], bvB[2][2];
  for (int t = 0; t < KT; ++t) {
    const int buf = t & 1, nbuf = buf ^ 1;
    const bool pf = (t + 1 < KT);

    // ---- tile entry: 2 stages ahead, then wait for tile-t's 8
    if (pf) {
      stageA(t + 1, nbuf, 0); stageA(t + 1, nbuf, 1);
      asm volatile("s_waitcnt vmcnt(2)" ::: "memory");
    } else {
      asm volatile("s_waitcnt vmcnt(0)" ::: "memory");
    }
    __builtin_amdgcn_s_barrier();

    // ---- phase 0: (m0-3 x n0-1)
#pragma unroll
    for (int mm = 0; mm < 4; ++mm)
#pragma unroll
      for (int kk = 0; kk < 2; ++kk) avA[mm][kk] = ldA(buf, mm, kk);
#pragma unroll
    for (int nn = 0; nn < 2; ++nn)
#pragma unroll
      for (int kk = 0; kk < 2; ++kk) bvA[nn][kk] = ldB(buf, nn, kk);
    __builtin_amdgcn_s_setprio(1);
#pragma unroll
    for (int mm = 0; mm < 4; ++mm)
#pragma unroll
      for (int nn = 0; nn < 2; ++nn)
#pragma unroll
        for (int kk = 0; kk < 2; ++kk)
          acc[mm][nn] = __builtin_amdgcn_mfma_f32_16x16x32_f16(avA[mm][kk], bvA[nn][kk], acc[mm][nn], 0, 0, 0);
    __builtin_amdgcn_s_setprio(0);
#pragma unroll
    for (int mm = 0; mm < 4; ++mm)
#pragma unroll
      for (int kk = 0; kk < 2; ++kk) avB[mm][kk] = ldA(buf, 4 + mm, kk);
    if (pf) { stageA(t + 1, nbuf, 2); stageA(t + 1, nbuf, 3); }
    asm volatile("" ::: "memory");
    __builtin_amdgcn_s_barrier();

    // ---- phase 1: (m4-7 x n0-1)
    __builtin_amdgcn_s_setprio(1);
#pragma unroll
    for (int mm = 0; mm < 4; ++mm)
#pragma unroll
      for (int nn = 0; nn < 2; ++nn)
#pragma unroll
        for (int kk = 0; kk < 2; ++kk)
          acc[4 + mm][nn] = __builtin_amdgcn_mfma_f32_16x16x32_f16(avB[mm][kk], bvA[nn][kk], acc[4 + mm][nn], 0, 0, 0);
    __builtin_amdgcn_s_setprio(0);
#pragma unroll
    for (int nn = 0; nn < 2; ++nn)
#pragma unroll
      for (int kk = 0; kk < 2; ++kk) bvB[nn][kk] = ldB(buf, 2 + nn, kk);
    if (pf) { stageB(t + 1, nbuf, 0); stageB(t + 1, nbuf, 1); }
    asm volatile("" ::: "memory");
    __builtin_amdgcn_s_barrier();

    // ---- phase 2: (m4-7 x n2-3)
    __builtin_amdgcn_s_setprio(1);
#pragma unroll
    for (int mm = 0; mm < 4; ++mm)
#pragma unroll
      for (int nn = 0; nn < 2; ++nn)
#pragma unroll
        for (int kk = 0; kk < 2; ++kk)
          acc[4 + mm][2 + nn] = __builtin_amdgcn_mfma_f32_16x16x32_f16(avB[mm][kk], bvB[nn][kk], acc[4 + mm][2 + nn], 0, 0, 0);
    __builtin_amdgcn_s_setprio(0);
#pragma unroll
    for (int mm = 0; mm < 4; ++mm)
#pragma unroll
      for (int kk = 0; kk < 2; ++kk) avA[mm][kk] = ldA(buf, mm, kk);
    if (pf) { stageB(t + 1, nbuf, 2); stageB(t + 1, nbuf, 3); }
    asm volatile("" ::: "memory");
    __builtin_amdgcn_s_barrier();

    // ---- phase 3: (m0-3 x n2-3)
    __builtin_amdgcn_s_setprio(1);
#pragma unroll
    for (int mm = 0; mm < 4; ++mm)
#pragma unroll
      for (int nn = 0; nn < 2; ++nn)
#pragma unroll
        for (int kk = 0; kk < 2; ++kk)
          acc[mm][2 + nn] = __builtin_amdgcn_mfma_f32_16x16x32_f16(avA[mm][kk], bvB[nn][kk], acc[mm][2 + nn], 0, 0, 0);
    __builtin_amdgcn_s_setprio(0);
  }

  if (EPI == 0) {
#pragma unroll
    for (int m = 0; m < 8; ++m) {
#pragma unroll
      for (int j = 0; j < 4; ++j) {
        int row = brow + wm * 128 + m * 16 + lk * 4 + j;
        if (MB && row >= M) continue;
        float* dst = C + (size_t)row * N + bcol + wn * 64 + lq;
#pragma unroll
        for (int n = 0; n < 4; ++n) dst[n * 16] = acc[m][n][j];
      }
    }
  } else if (EPI == 1) {
    __shared__ float ssq[256][4];
#pragma unroll
    for (int m = 0; m < 8; ++m)
#pragma unroll
      for (int j = 0; j < 4; ++j) {
        int lr = wm * 128 + m * 16 + lk * 4 + j;
        float pp = 0.f;
#pragma unroll
        for (int n = 0; n < 4; ++n) pp += acc[m][n][j] * acc[m][n][j];
        pp += __shfl_xor(pp, 1);
        pp += __shfl_xor(pp, 2);
        pp += __shfl_xor(pp, 4);
        pp += __shfl_xor(pp, 8);
        if (lq == 0) ssq[lr][wn] = pp;
      }
    asm volatile("" ::: "memory");
    __builtin_amdgcn_s_barrier();
    const int hh = wn >> 1;
    float wv[4];
#pragma unroll
    for (int n = 0; n < 4; ++n) wv[n] = wvec[(wn * 64 + n * 16 + lq) & 127];
#pragma unroll
    for (int m = 0; m < 8; ++m)
#pragma unroll
      for (int j = 0; j < 4; ++j) {
        int lr = wm * 128 + m * 16 + lk * 4 + j;
        float ss = ssq[lr][hh * 2] + ssq[lr][hh * 2 + 1];
        float rs = rsqrtf(ss * (1.0f / 128.0f) + 1e-5f) *
                   (0.08838834764831845f * 1.4426950408889634f);
        f16* dst = Ch + (size_t)(brow + lr) * N + bcol + wn * 64 + lq;
#pragma unroll
        for (int n = 0; n < 4; ++n) dst[n * 16] = (f16)(acc[m][n][j] * rs * wv[n]);
      }
  } else {
    // EPI==2: KV path.  rows r = b*1601+s (M=6404); K half: RMS -> Kf; V half -> Vtf^T
    const bool isK = (bcol < 1024);
    __shared__ float ssq[256][4];
    if (isK) {
#pragma unroll
      for (int m = 0; m < 8; ++m)
#pragma unroll
        for (int j = 0; j < 4; ++j) {
          int lr = wm * 128 + m * 16 + lk * 4 + j;
          float pp = 0.f;
#pragma unroll
          for (int n = 0; n < 4; ++n) pp += acc[m][n][j] * acc[m][n][j];
          pp += __shfl_xor(pp, 1);
          pp += __shfl_xor(pp, 2);
          pp += __shfl_xor(pp, 4);
          pp += __shfl_xor(pp, 8);
          if (lq == 0) ssq[lr][wn] = pp;
        }
      asm volatile("" ::: "memory");
      __builtin_amdgcn_s_barrier();
    }
    const int hh = wn >> 1;
    float wv[4];
    if (isK) {
#pragma unroll
      for (int n = 0; n < 4; ++n) wv[n] = wvec[(wn * 64 + n * 16 + lq) & 127];
    }
#pragma unroll
    for (int m = 0; m < 8; ++m) {
#pragma unroll
      for (int j = 0; j < 4; ++j) {
        int lr = wm * 128 + m * 16 + lk * 4 + j;
        int r = brow + lr;
        if (r >= M) continue;
        unsigned bb = (unsigned)r / 1601u;
        unsigned s = (unsigned)r - bb * 1601u;
        if (isK) {
          float ss = ssq[lr][hh * 2] + ssq[lr][hh * 2 + 1];
          float rs = rsqrtf(ss * (1.0f / 128.0f) + 1e-5f);
#pragma unroll
          for (int n = 0; n < 4; ++n) {
            int col = wn * 64 + n * 16 + lq;
            int kvh = (bcol + col) >> 7;
            int d = col & 127;
            Ch[((size_t)(bb * 8 + kvh) * 1664 + s) * 128 + d] =
                (f16)(acc[m][n][j] * rs * wv[n]);
          }
        } else {
#pragma unroll
          for (int n = 0; n < 4; ++n) {
            int col = bcol - 1024 + wn * 64 + n * 16 + lq;
            int kvh = col >> 7;
            int d = col & 127;
            Vtf[((size_t)(bb * 8 + kvh) * 128 + d) * 1664 + s] = (f16)acc[m][n][j];
          }
        }
      }
    }
  }
}

// ---------------------------------------------------------------- flash attention
// (r13 state, best measured: 163 us, conflicts 8.3M)  4 waves x 32 q rows,
// KVBLK=64, K/V double-buffered, counted vmcnt(8).  LDS 80 KB, 2 blocks/CU.
// STATIC-MAX softmax (|logit| <= 16.33 bounded by RMS norms; -8 in C-init).
// P swizzle: write swzW = lk<<5 (bijective in lk); read same function of row.
// r15 lesson: porting this P swizzle to the 8-wave shape did NOT reduce
// conflicts (14.9M) -- the 4-wave geometry itself is part of the win.
__global__ __launch_bounds__(256, 2) void attn_kernel(const f16* __restrict__ Qf,
                                                      const f16* __restrict__ Kf,
                                                      const f16* __restrict__ Vtf,
                                                      f16* __restrict__ Oa) {
  __shared__ f16 Ksm[2][64][128];  // 32 KB dbuf, 256 B rows, XOR-swizzled
  __shared__ f16 Vsm[2][128][64];  // 32 KB dbuf, V^T [d][kv], swizzled
  __shared__ f16 Psm[4][32][64];   // 8 KB per-wave P
  const int p = blockIdx.x;              // 0..1023
  const int L = (p & 7) * 128 + (p >> 3);
  const int qt = L & 7, h = (L >> 3) & 31, b = L >> 8;
  const int kvh = h >> 2;  // G = 4
  const int tid = threadIdx.x;
  const int l = tid & 63, w = tid >> 6;  // 4 waves
  const int lq = l & 15, lk = l >> 4;

  // Q fragments: wave w owns 32 q rows (qt*128 + w*32 ..)
  f16x8 qreg[2][4];
  const f16* Qbase = Qf + ((size_t)(b * 1024 + qt * 128 + w * 32)) * 4096 + h * 128;
#pragma unroll
  for (int qm = 0; qm < 2; ++qm)
#pragma unroll
    for (int ks = 0; ks < 4; ++ks)
      qreg[qm][ks] = *reinterpret_cast<const f16x8*>(
          Qbase + (size_t)(qm * 16 + lq) * 4096 + ks * 32 + lk * 8);

  const f16* Kb = Kf + (size_t)(b * 8 + kvh) * (1664 * 128);
  const f16* Vb = Vtf + (size_t)(b * 8 + kvh) * (128 * 1664);

  f32x4 o[2][8];
  f32x4 zf = {0.f, 0.f, 0.f, 0.f};
  f32x4 neg8 = {-8.f, -8.f, -8.f, -8.f};
#pragma unroll
  for (int qm = 0; qm < 2; ++qm)
#pragma unroll
    for (int dn = 0; dn < 8; ++dn) o[qm][dn] = zf;
  float lrow[2][4];  // per-lane partial row sums, reduced once in epilogue
#pragma unroll
  for (int qm = 0; qm < 2; ++qm)
#pragma unroll
    for (int j = 0; j < 4; ++j) lrow[qm][j] = 0.f;

  char* Pw = (char*)(&Psm[w][0][0]);   // 32 rows x 128 B
  const int swzR = (lq & 7) << 4;      // K/V read swizzle

  auto stageK = [&](int t, int buf) {  // 16 KB over 4 waves: 4 issues, 4 rows each
#pragma unroll
    for (int i = 0; i < 4; ++i) {
      int row = w * 16 + i * 4 + lk;
      int cb = (lq * 16) ^ ((row & 7) << 4);
      gload_lds16(Kb + (size_t)(t * 64 + row) * 128 + (cb >> 1),
                  (char*)(&Ksm[buf][0][0]) + w * 4096 + i * 1024);
    }
  };
  auto stageV = [&](int t, int buf) {  // 16 KB over 4 waves: 4 issues, 8 rows each
#pragma unroll
    for (int i = 0; i < 4; ++i) {
      int r = w * 32 + i * 8 + (l >> 3);
      int cb = ((l & 7) * 16) ^ ((r & 7) << 4);
      gload_lds16(Vb + (size_t)r * 1664 + t * 64 + (cb >> 1),
                  (char*)(&Vsm[buf][0][0]) + w * 4096 + i * 1024);
    }
  };

  stageK(0, 0);
  stageV(0, 0);
  int cur = 0;
  for (int t = 0; t < 26; ++t) {
    if (t < 25) {
      stageK(t + 1, cur ^ 1);                       // 8 issues for tile t+1
      stageV(t + 1, cur ^ 1);
      asm volatile("s_waitcnt vmcnt(8)" ::: "memory");  // own tile-t loads done
    } else {
      asm volatile("s_waitcnt vmcnt(0)" ::: "memory");
    }
    __builtin_amdgcn_s_barrier();                   // all waves' tile-t loads done

    // ---- S = Q K^T - 8 (fp32 accum, static-max offset in C-init)
    f32x4 s[2][4];
#pragma unroll
    for (int qm = 0; qm < 2; ++qm)
#pragma unroll
      for (int kn = 0; kn < 4; ++kn) s[qm][kn] = neg8;
    __builtin_amdgcn_s_setprio(1);
#pragma unroll
    for (int ks = 0; ks < 4; ++ks) {
      f16x8 bf[4];
#pragma unroll
      for (int kn = 0; kn < 4; ++kn)
        bf[kn] = *reinterpret_cast<const f16x8*>(
            (char*)(&Ksm[cur][0][0]) + (kn * 16 + lq) * 256 + ((ks * 64 + lk * 16) ^ swzR));
#pragma unroll
      for (int qm = 0; qm < 2; ++qm)
#pragma unroll
        for (int kn = 0; kn < 4; ++kn)
          s[qm][kn] = __builtin_amdgcn_mfma_f32_16x16x32_f16(qreg[qm][ks], bf[kn], s[qm][kn], 0, 0, 0);
    }
    __builtin_amdgcn_s_setprio(0);

    // ---- mask tail (valid kv < 1601; tile 25 covers 1600..1663 -> local < 1)
    if (t == 25) {
#pragma unroll
      for (int kn = 0; kn < 4; ++kn) {
        bool valid = (kn * 16 + lq) < 1;
#pragma unroll
        for (int qm = 0; qm < 2; ++qm)
#pragma unroll
          for (int j = 0; j < 4; ++j) s[qm][kn][j] = valid ? s[qm][kn][j] : -1e30f;
      }
    }

    // ---- P = 2^s; per-lane partial sums; P write with conflict-free swizzle
#pragma unroll
    for (int qm = 0; qm < 2; ++qm) {
#pragma unroll
      for (int j = 0; j < 4; ++j) {
        float rsum = 0.f;
#pragma unroll
        for (int kn = 0; kn < 4; ++kn) {
          float pv = exp2f(s[qm][kn][j]);
          s[qm][kn][j] = pv;
          rsum += pv;
        }
        lrow[qm][j] += rsum;
        int prow = qm * 16 + lk * 4 + j;
        int swzW = lk << 5;  // = ((prow>>2)&3)<<5, bijective in lk
#pragma unroll
        for (int kn = 0; kn < 4; ++kn)
          *reinterpret_cast<f16*>(Pw + prow * 128 + (((kn * 16 + lq) * 2) ^ swzW)) =
              (f16)s[qm][kn][j];
      }
    }

    // ---- O += P V   (pa read uses same swizzle function of row)
    __builtin_amdgcn_s_setprio(1);
#pragma unroll
    for (int c = 0; c < 2; ++c) {
      f16x8 pa[2];
#pragma unroll
      for (int qm = 0; qm < 2; ++qm) {
        int prow = qm * 16 + lq;
        pa[qm] = *reinterpret_cast<const f16x8*>(
            Pw + prow * 128 + ((c * 64 + lk * 16) ^ (((lq >> 2) & 3) << 5)));
      }
      f16x8 vb[8];
#pragma unroll
      for (int dn = 0; dn < 8; ++dn)
        vb[dn] = *reinterpret_cast<const f16x8*>(
            (char*)(&Vsm[cur][0][0]) + (dn * 16 + lq) * 128 + ((c * 64 + lk * 16) ^ swzR));
#pragma unroll
      for (int qm = 0; qm < 2; ++qm)
#pragma unroll
        for (int dn = 0; dn < 8; ++dn)
          o[qm][dn] = __builtin_amdgcn_mfma_f32_16x16x32_f16(pa[qm], vb[dn], o[qm][dn], 0, 0, 0);
    }
    __builtin_amdgcn_s_setprio(0);
    __builtin_amdgcn_s_barrier();   // all reads of buf `cur` done before next staging
    cur ^= 1;
  }

  // ---- epilogue: reduce lrow partials across the 16-lane row group, then O/l
#pragma unroll
  for (int qm = 0; qm < 2; ++qm) {
#pragma unroll
    for (int j = 0; j < 4; ++j) {
      float fl = lrow[qm][j];
      fl += __shfl_xor(fl, 1);
      fl += __shfl_xor(fl, 2);
      fl += __shfl_xor(fl, 4);
      fl += __shfl_xor(fl, 8);
      float il = 1.0f / fl;
      int token = b * 1024 + qt * 128 + w * 32 + qm * 16 + lk * 4 + j;
      f16* dst = Oa + (size_t)token * 4096 + h * 128;
#pragma unroll
      for (int dn = 0; dn < 8; ++dn) dst[dn * 16 + lq] = (f16)(o[qm][dn][j] * il);
    }
  }
}

// ---------------------------------------------------------------- launch
extern "C" void kernel_launch(void* const* d_in, const int* in_sizes, int n_in,
                              void* d_out, int out_size, void* d_ws, size_t ws_size,
                              hipStream_t stream) {
  const float* hidden = (const float*)d_in[0];  // [4,1024,4096]
  const float* cross  = (const float*)d_in[1];  // [4,1601,4096]
  const float* wqkv   = (const float*)d_in[2];  // [6144,4096]
  const float* wo     = (const float*)d_in[3];  // [4096,4096]
  const float* qw     = (const float*)d_in[4];  // [128]
  const float* kw     = (const float*)d_in[5];  // [128]

  char* ws = (char*)d_ws;
  f16* hidden_h = (f16*)(ws + 0);            // 33.55 MB -> attn_h after Q-proj
  f16* attn_h   = hidden_h;
  f16* wqkv_h = (f16*)(ws + 33554432);       // 50.33 MB
  f16* cross_h = (f16*)(ws + 83886080);      // 52.46 MB (-> wo_h in fallback)
  f16* k_h  = (f16*)(ws + 136347648);        // 13.63 MB
  f16* vt_h = (f16*)(ws + 136347648 + 13631488);  // 13.63 MB
  f16* q_h = (f16*)d_out;  // consumed by attn before O-proj overwrites d_out

  // wo_h: own region at +163.6 MB when workspace allows (fuses its convert
  // into cvtzero, before KV-proj); else fallback = convert after KV-proj into
  // the dead cross_h region.
  const bool fuse_wo = (ws_size >= (size_t)197165056);
  f16* wo_h = fuse_wo ? (f16*)(ws + 163610624) : (f16*)(ws + 83886080);

  // 1) fused converts (hidden, cross, wqkv [, wo]) + zero-fill of K/Vt pads
  cvtzero_kernel<<<2048, 256, 0, stream>>>(hidden, hidden_h, cross, cross_h,
                                           wqkv, wqkv_h, wo, wo_h,
                                           fuse_wo ? 4194304 : 0,
                                           (float4*)(ws + 136347648));
  // 2) KV projection with fused K-RMS + V-transpose epilogue
  gemm256<true, 2><<<dim3(8, 26), 512, 0, stream>>>(
      cross_h, wqkv_h + (size_t)4096 * 4096, nullptr, k_h, kw, vt_h, 6404, 2048, 4096);
  // 3) wo convert fallback (only when not fused)
  if (!fuse_wo)
    cvt_kernel<<<2048, 256, 0, stream>>>(wo, wo_h, 16777216 / 4);
  // 4) Q projection with fused RMS-norm (+scale*log2e) -> f16 q_h (in d_out)
  gemm256<false, 1><<<dim3(16, 16), 512, 0, stream>>>(
      hidden_h, wqkv_h, nullptr, q_h, qw, nullptr, 4096, 4096, 4096);
  // 5) attention (r13 state: 4-wave blocks, dbuf K/V, conflict-free P swizzle)
  attn_kernel<<<1024, 256, 0, stream>>>(q_h, k_h, vt_h, attn_h);
  // 6) output projection -> d_out
  gemm256<false, 0><<<dim3(16, 16), 512, 0, stream>>>(
      attn_h, wo_h, (float*)d_out, nullptr, nullptr, nullptr, 4096, 4096, 4096);
}